// Round 5
// baseline (24.481 us; speedup 1.0000x reference)
//
#include <hip/hip_runtime.h>

// Problem geometry (f32):
//   x:   [8, 16, 3, 224, 224]
//   out: [8, 16, 224, 224, 3]  (permute 0,1,4,3,2)
// batch 0: y[0]=x[0]; y[t] = x[t] - 0.4*y[t-1] + 3   (elementwise c,h,w)
// batches 1..6: zeros
// batch 7: z[0]=0; z[t] = 3 - 0.4*z[t-1], broadcast over (w,h,c)
//
// Round 5 (= round 4 with compile fix): batch-0 stores via one-barrier LDS
// staging -> aligned 16-B stores (each (t,w) 96-B run = 6 aligned vec4s),
// replacing 48 scattered 4-B stores/thread. Rotate-by-w slot swizzle
// preserves alignment while spreading LDS banks. All output stores
// nontemporal via clang ext_vector_type (HIP float4 is a struct and
// __builtin_nontemporal_store rejects it). Tile spacing bid%9 (coprime to
// 8 XCDs) kept from round 3.

typedef float fx4 __attribute__((ext_vector_type(4)));

#define SP        150528    // 3*224*224 elements per (b,t) slice
#define TT        16
#define CH_STRIDE 50176     // 224*224
#define BSTRIDE   2408448   // 16*SP elements per batch

#define NWT    7            // w tiles (224/32)
#define NTILES 196          // 28 h-tiles x 7 w-tiles

#define FILL4   4214784     // 7 * 16*SP/4 vec4s (batches 1..7)
#define TSLICE4 37632       // SP/4
#define NBLOCKS 2048
#define NFILL   (NBLOCKS - NTILES)   // 1852
#define RFILL   2276                 // ceil(FILL4/NFILL)
#define SPREAD  9                    // coprime to 8 -> uniform over XCDs

__global__ __launch_bounds__(256) void temporal_fused(
    const float* __restrict__ x, float* __restrict__ out)
{
    const int tid = threadIdx.x;
    const int bid = blockIdx.x;

    // LDS: [t][w][6 slots][4 floats] = 16*32*24 floats = 48 KiB
    __shared__ float lds[TT * 32 * 24];

    const bool is_tile = (bid % SPREAD == 0) && (bid / SPREAD) < NTILES;

    if (is_tile) {
        // ------------- batch-0 recurrence, tile = 8h x 32w, 3c/thread -----
        const int tileid = bid / SPREAD;
        const int h0 = (tileid / NWT) * 8;
        const int w0 = (tileid % NWT) * 32;
        const int dw = tid & 31;       // w offset 0..31
        const int hh = tid >> 5;       // h offset 0..7
        const int rbase = (h0 + hh) * 224 + w0 + dw;

        // all 48 loads independent -> single HBM latency
        float v[TT][3];
        #pragma unroll
        for (int t = 0; t < TT; ++t) {
            #pragma unroll
            for (int c = 0; c < 3; ++c)
                v[t][c] = x[t * SP + c * CH_STRIDE + rbase];
        }

        // LDS write bases: logical idx = hh*3+c in [0,24); slot s=idx>>2,
        // phys slot = (s+dw)%6 (rotate swizzle, alignment-preserving)
        int wbase[3];
        #pragma unroll
        for (int c = 0; c < 3; ++c) {
            const int idx = hh * 3 + c;
            const int s = idx >> 2, o = idx & 3;
            wbase[c] = dw * 24 + ((s + dw) % 6) * 4 + o;
        }

        float y0 = v[0][0], y1 = v[0][1], y2 = v[0][2];
        #pragma unroll
        for (int t = 0; t < TT; ++t) {
            if (t > 0) {
                y0 = v[t][0] - 0.4f * y0 + 3.0f;
                y1 = v[t][1] - 0.4f * y1 + 3.0f;
                y2 = v[t][2] - 0.4f * y2 + 3.0f;
            }
            lds[t * 768 + wbase[0]] = y0;
            lds[t * 768 + wbase[1]] = y1;
            lds[t * 768 + wbase[2]] = y2;
        }
        __syncthreads();

        // readout: 16t x 32w x 6 vec4 = 3072 vec4s = 12 iters x 256 thr
        const fx4* lds4 = reinterpret_cast<const fx4*>(lds);
        const int ob0 = w0 * 672 + h0 * 3;
        #pragma unroll
        for (int k = 0; k < 12; ++k) {
            const int j = tid + k * 256;       // < 3072
            const int t = j / 192;
            const int r = j - t * 192;
            const int w = r / 6;
            const int piece = r - w * 6;
            const int phys = (piece + w) % 6;
            const fx4 f4 = lds4[(t * 768 + w * 24 + phys * 4) >> 2];
            fx4* dst = reinterpret_cast<fx4*>(
                out + t * SP + ob0 + w * 672 + piece * 4);
            __builtin_nontemporal_store(f4, dst);
        }
        return;
    }

    // ---------------- fill: batches 1..6 zeros, batch 7 broadcast z[t] ----
    const int tiles_before = min((bid + SPREAD - 1) / SPREAD, NTILES);
    const int fidx = bid - tiles_before;          // 0..NFILL-1

    fx4* out4 = reinterpret_cast<fx4*>(out + BSTRIDE); // batch-1 start
    int q   = fidx * RFILL;
    int end = q + RFILL;
    if (end > FILL4) end = FILL4;

    while (q < end) {
        const int slice = q / TSLICE4;            // 0..111 = (batch-1)*16 + t
        int send = (slice + 1) * TSLICE4;
        if (send > end) send = end;
        float zv = 0.0f;
        if ((slice >> 4) == 6) {                  // batch 7
            const int t = slice & 15;
            float z = 0.0f;
            for (int i = 0; i < t; ++i) z = 3.0f - 0.4f * z;
            zv = z;
        }
        fx4 val;
        val.x = zv; val.y = zv; val.z = zv; val.w = zv;
        for (int i = q + tid; i < send; i += 256)
            __builtin_nontemporal_store(val, &out4[i]);
        q = send;
    }
}

extern "C" void kernel_launch(void* const* d_in, const int* in_sizes, int n_in,
                              void* d_out, int out_size, void* d_ws, size_t ws_size,
                              hipStream_t stream) {
    const float* x = (const float*)d_in[0];
    float* out = (float*)d_out;
    temporal_fused<<<NBLOCKS, 256, 0, stream>>>(x, out);
}

// Round 6
// 17.314 us; speedup vs baseline: 1.4140x; 1.4140x over previous
//
#include <hip/hip_runtime.h>

// Problem geometry (f32):
//   x:   [8, 16, 3, 224, 224]
//   out: [8, 16, 224, 224, 3]  (permute 0,1,4,3,2)
// batch 0: y[0]=x[0]; y[t] = x[t] - 0.4*y[t-1] + 3   (elementwise c,h,w)
// batches 1..6: zeros
// batch 7: z[0]=0; z[t] = 3 - 0.4*z[t-1], broadcast over (w,h,c)
//
// Round 6: round-3 frame (spacing 9, 2048 blocks, plain stores, batched
// 48 loads) + tile stores via SMALL LDS staging: 4 phases x 4 t-slices,
// 12 KiB LDS (no occupancy hit, unlike round 5's 48 KiB), vec4 readout
// (each (t,w) 96-B run = 6 aligned 16-B stores). NO nontemporal anywhere —
// round 5 confounded NT (L2 bypass -> partial-line RMW) with the staging.

typedef float fx4 __attribute__((ext_vector_type(4)));

#define SP        150528    // 3*224*224 elements per (b,t) slice
#define TT        16
#define CH_STRIDE 50176     // 224*224
#define BSTRIDE   2408448   // 16*SP elements per batch

#define NWT    7            // w tiles (224/32)
#define NTILES 196          // 28 h-tiles x 7 w-tiles

#define FILL4   4214784     // 7 * 16*SP/4 vec4s (batches 1..7)
#define TSLICE4 37632       // SP/4
#define NBLOCKS 2048
#define NFILL   (NBLOCKS - NTILES)   // 1852
#define RFILL   2276                 // ceil(FILL4/NFILL)
#define SPREAD  9                    // coprime to 8 -> uniform over XCDs

__global__ __launch_bounds__(256) void temporal_fused(
    const float* __restrict__ x, float* __restrict__ out)
{
    const int tid = threadIdx.x;
    const int bid = blockIdx.x;

    // 12 KiB: 4 t-slices of [32 w][6 slots][4 floats]
    __shared__ float lds[4 * 768];

    const bool is_tile = (bid % SPREAD == 0) && (bid / SPREAD) < NTILES;

    if (is_tile) {
        // ------------- batch-0 recurrence, tile = 8h x 32w, 3c/thread -----
        const int tileid = bid / SPREAD;
        const int h0 = (tileid / NWT) * 8;
        const int w0 = (tileid % NWT) * 32;
        const int dw = tid & 31;       // w offset 0..31
        const int hh = tid >> 5;       // h offset 0..7
        const int rbase = (h0 + hh) * 224 + w0 + dw;

        // all 48 loads independent -> single HBM latency
        float v[TT][3];
        #pragma unroll
        for (int t = 0; t < TT; ++t) {
            #pragma unroll
            for (int c = 0; c < 3; ++c)
                v[t][c] = x[t * SP + c * CH_STRIDE + rbase];
        }

        // LDS write bases: logical idx = hh*3+c in [0,24); slot s=idx>>2,
        // phys slot = (s+dw)%6 (rotate swizzle, alignment-preserving;
        // verified correct in round 5, absmax 0)
        int wbase[3];
        #pragma unroll
        for (int c = 0; c < 3; ++c) {
            const int idx = hh * 3 + c;
            const int s = idx >> 2, o = idx & 3;
            wbase[c] = dw * 24 + ((s + dw) % 6) * 4 + o;
        }

        const int ob0 = w0 * 672 + h0 * 3;
        float y0 = 0.f, y1 = 0.f, y2 = 0.f;

        #pragma unroll
        for (int p = 0; p < 4; ++p) {
            // compute 4 t-slices into LDS
            #pragma unroll
            for (int tl = 0; tl < 4; ++tl) {
                const int t = p * 4 + tl;
                if (t == 0) { y0 = v[0][0]; y1 = v[0][1]; y2 = v[0][2]; }
                else {
                    y0 = v[t][0] - 0.4f * y0 + 3.0f;
                    y1 = v[t][1] - 0.4f * y1 + 3.0f;
                    y2 = v[t][2] - 0.4f * y2 + 3.0f;
                }
                lds[tl * 768 + wbase[0]] = y0;
                lds[tl * 768 + wbase[1]] = y1;
                lds[tl * 768 + wbase[2]] = y2;
            }
            __syncthreads();

            // readout: 4t x 32w x 6 vec4 = 768 vec4s = 3 iters x 256 thr
            const fx4* lds4 = reinterpret_cast<const fx4*>(lds);
            #pragma unroll
            for (int k = 0; k < 3; ++k) {
                const int j = tid + k * 256;       // < 768
                const int tl = j / 192;
                const int r = j - tl * 192;
                const int w = r / 6;
                const int piece = r - w * 6;
                const int phys = (piece + w) % 6;
                const fx4 f4 = lds4[(tl * 768 + w * 24 + phys * 4) >> 2];
                *reinterpret_cast<fx4*>(
                    out + (p * 4 + tl) * SP + ob0 + w * 672 + piece * 4) = f4;
            }
            __syncthreads();   // protect LDS before next phase overwrites
        }
        return;
    }

    // ---------------- fill: batches 1..6 zeros, batch 7 broadcast z[t] ----
    const int tiles_before = min((bid + SPREAD - 1) / SPREAD, NTILES);
    const int fidx = bid - tiles_before;          // 0..NFILL-1

    fx4* out4 = reinterpret_cast<fx4*>(out + BSTRIDE); // batch-1 start
    int q   = fidx * RFILL;
    int end = q + RFILL;
    if (end > FILL4) end = FILL4;

    while (q < end) {
        const int slice = q / TSLICE4;            // 0..111 = (batch-1)*16 + t
        int send = (slice + 1) * TSLICE4;
        if (send > end) send = end;
        float zv = 0.0f;
        if ((slice >> 4) == 6) {                  // batch 7
            const int t = slice & 15;
            float z = 0.0f;
            for (int i = 0; i < t; ++i) z = 3.0f - 0.4f * z;
            zv = z;
        }
        fx4 val;
        val.x = zv; val.y = zv; val.z = zv; val.w = zv;
        for (int i = q + tid; i < send; i += 256)
            out4[i] = val;
        q = send;
    }
}

extern "C" void kernel_launch(void* const* d_in, const int* in_sizes, int n_in,
                              void* d_out, int out_size, void* d_ws, size_t ws_size,
                              hipStream_t stream) {
    const float* x = (const float*)d_in[0];
    float* out = (float*)d_out;
    temporal_fused<<<NBLOCKS, 256, 0, stream>>>(x, out);
}